// Round 2
// baseline (2476.347 us; speedup 1.0000x reference)
//
#include <hip/hip_runtime.h>
#include <hip/hip_bf16.h>

#define NH_N 50000
#define NV_N 100000
#define NE_N 150000
#define E_N  300000
#define HD   128
#define NLAY 3
#define NBAT 256
#define NSCA 22

typedef unsigned short u16;
typedef __attribute__((ext_vector_type(8))) short short8v;
typedef __attribute__((ext_vector_type(4))) float f32x4;

__device__ inline u16 f2bf(float f) { __hip_bfloat16 h = __float2bfloat16(f); return *(u16*)&h; }
__device__ inline float bf2f(u16 u) { __hip_bfloat16 h; *(u16*)&h = u; return __bfloat162float(h); }

// ---------------- zero fill ----------------
__global__ void zero_kernel(int* __restrict__ p, int n) {
  int i = blockIdx.x * 256 + threadIdx.x;
  if (i < n) p[i] = 0;
}

// ---------------- weight prep: transpose + hi/lo split to bf16 ----------------
// Wt layout: [mat(l*4+rel)][s(0=Wl,1=Wr)][n(128)][k'(256: 0..127 hi, 128..255 lo)]
__global__ void wprep_kernel(const float* __restrict__ Wl, const float* __restrict__ Wr,
                             u16* __restrict__ Wt) {
  int mat = blockIdx.x, s = blockIdx.y;
  const float* Wsrc = (s ? Wr : Wl) + (size_t)mat * HD * HD;
  u16* Wd = Wt + ((size_t)mat * 2 + s) * HD * 256;
  int tid = threadIdx.x;
  for (int i = 0; i < 64; ++i) {
    int idx = i * 256 + tid;
    int k = idx >> 7, n = idx & 127;
    float wv = Wsrc[idx];
    u16 hi = f2bf(wv);
    float lo = wv - bf2f(hi);
    Wd[(size_t)n * 256 + k] = hi;
    Wd[(size_t)n * 256 + 128 + k] = f2bf(lo);
  }
}

// ---------------- input projection: out = relu(x @ W + b), bf16 out ----------------
__global__ void proj_kernel(const float* __restrict__ x, const float* __restrict__ W,
                            const float* __restrict__ bias, u16* __restrict__ out,
                            int n, int F) {
  int node = blockIdx.x * 2 + (threadIdx.x >> 7);
  int h = threadIdx.x & 127;
  if (node >= n) return;
  float acc = bias[h];
  const float* xr = x + (size_t)node * F;
  for (int f = 0; f < F; ++f) acc = fmaf(xr[f], W[f * HD + h], acc);
  out[(size_t)node * HD + h] = f2bf(fmaxf(acc, 0.0f));
}

// ---------------- CSR build ----------------
__global__ void hist_kernel(const int* __restrict__ dst, int* __restrict__ deg, int n) {
  int e = blockIdx.x * 256 + threadIdx.x;
  if (e < n) atomicAdd(&deg[dst[e]], 1);
}

__global__ void scan_block_kernel(const int* __restrict__ deg, int* __restrict__ rp,
                                  int* __restrict__ bsums, int n) {
  __shared__ int buf[256];
  int tid = threadIdx.x;
  int i = blockIdx.x * 256 + tid;
  buf[tid] = (i < n) ? deg[i] : 0;
  __syncthreads();
  #pragma unroll
  for (int off = 1; off < 256; off <<= 1) {
    int t = (tid >= off) ? buf[tid - off] : 0;
    __syncthreads();
    buf[tid] += t;
    __syncthreads();
  }
  if (i < n) rp[i + 1] = buf[tid];
  if (tid == 255) bsums[blockIdx.x] = buf[255];
}

__global__ void scan_sums_kernel(int* __restrict__ bsums, int nb) {
  __shared__ int buf[256];
  __shared__ int carry_s;
  int tid = threadIdx.x;
  if (tid == 0) carry_s = 0;
  __syncthreads();
  for (int base = 0; base < nb; base += 256) {
    int i = base + tid;
    buf[tid] = (i < nb) ? bsums[i] : 0;
    __syncthreads();
    for (int off = 1; off < 256; off <<= 1) {
      int t = (tid >= off) ? buf[tid - off] : 0;
      __syncthreads();
      buf[tid] += t;
      __syncthreads();
    }
    int c = carry_s;
    if (i < nb) bsums[i] = buf[tid] + c;
    __syncthreads();
    if (tid == 255) carry_s = c + buf[255];
    __syncthreads();
  }
}

__global__ void scan_add_kernel(const int* __restrict__ bsums, int* __restrict__ rp, int n) {
  int i = blockIdx.x * 256 + threadIdx.x;
  if (i == 0) rp[0] = 0;
  if (i < n && blockIdx.x > 0) rp[i + 1] += bsums[blockIdx.x - 1];
}

__global__ void fill_csr_kernel(const int* __restrict__ src, const int* __restrict__ dst,
                                const int* __restrict__ rp, int* __restrict__ fil,
                                int* __restrict__ csr, int n) {
  int e = blockIdx.x * 256 + threadIdx.x;
  if (e >= n) return;
  int d = dst[e];
  int pos = rp[d] + atomicAdd(&fil[d], 1);
  csr[pos] = src[e];
}

// ---------------- mean aggregation (gather over CSR), bf16 in/out, fp32 accum ----------------
__global__ void agg_kernel(const u16* __restrict__ hsrc, const int* __restrict__ rp,
                           const int* __restrict__ csr, u16* __restrict__ mean, int n) {
  int node = blockIdx.x * 2 + (threadIdx.x >> 7);
  int h = threadIdx.x & 127;
  if (node >= n) return;
  int s0 = rp[node], s1 = rp[node + 1];
  float acc = 0.0f;
  for (int j = s0; j < s1; ++j) acc += bf2f(hsrc[(size_t)csr[j] * HD + h]);
  int c = s1 - s0; if (c < 1) c = 1;
  mean[(size_t)node * HD + h] = f2bf(acc / (float)c);
}

// ---------------- SAGE MFMA GEMM: out = epi(mean@Wl + xdst@Wr + b) ----------------
// block: 256 thr = 4 waves, tile 64 rows x 128 cols. wave (wr,wc) owns 32x64.
// K per half = 128, weight split hi+lo (two MFMAs, same acc).
// MODE 0: relu(t); MODE 1: raw t; MODE 2: relu(0.5*(t + out_prev))
template <int MODE>
__global__ __launch_bounds__(256)
void sage_mfma_kernel(const u16* __restrict__ Xmean, const u16* __restrict__ Xdst,
                      const u16* __restrict__ Wt, const float* __restrict__ bias,
                      u16* __restrict__ out, int M) {
  __shared__ u16 xs[64 * 128];  // 16KB, XOR-swizzled rows
  const int tid = threadIdx.x;
  const int lane = tid & 63;
  const int w = tid >> 6;
  const int wr = w >> 1;
  const int wc = w & 1;
  const int row0 = blockIdx.x * 64;
  const int l15 = lane & 15;
  const int l4 = lane >> 4;

  f32x4 acc[2][4];
  #pragma unroll
  for (int a = 0; a < 2; ++a)
    #pragma unroll
    for (int b = 0; b < 4; ++b) acc[a][b] = (f32x4){0.f, 0.f, 0.f, 0.f};

  int mrow[2];
  #pragma unroll
  for (int mi = 0; mi < 2; ++mi) mrow[mi] = wr * 32 + mi * 16 + l15;

  for (int half = 0; half < 2; ++half) {
    const u16* X = half ? Xdst : Xmean;
    const u16* Wh = Wt + (size_t)half * (HD * 256);
    __syncthreads();  // finish previous xs use before overwrite
    // stage 64x128 bf16 tile, swizzled: byte ^= (row&7)<<4
    #pragma unroll
    for (int i = 0; i < 4; ++i) {
      int idx = i * 256 + tid;     // 16B-chunk id
      int m = idx >> 4;
      int c = idx & 15;
      int gr = row0 + m; if (gr >= M) gr = M - 1;
      uint4 v = *(const uint4*)(X + (size_t)gr * HD + c * 8);
      int sb = m * 256 + ((c * 16) ^ ((m & 7) << 4));
      *(uint4*)((char*)xs + sb) = v;
    }
    __syncthreads();
    #pragma unroll
    for (int kw = 0; kw < 4; ++kw) {
      int kb = kw * 64 + l4 * 16;  // byte offset of this lane's 8 k-elems
      short8v a0 = *(const short8v*)((const char*)xs + mrow[0] * 256 + (kb ^ ((mrow[0] & 7) << 4)));
      short8v a1 = *(const short8v*)((const char*)xs + mrow[1] * 256 + (kb ^ ((mrow[1] & 7) << 4)));
      #pragma unroll
      for (int ni = 0; ni < 4; ++ni) {
        int n = wc * 64 + ni * 16 + l15;
        const u16* bp = Wh + (size_t)n * 256 + kw * 32 + l4 * 8;
        short8v bh = *(const short8v*)bp;
        short8v bl = *(const short8v*)(bp + 128);
        acc[0][ni] = __builtin_amdgcn_mfma_f32_16x16x32_bf16(a0, bh, acc[0][ni], 0, 0, 0);
        acc[1][ni] = __builtin_amdgcn_mfma_f32_16x16x32_bf16(a1, bh, acc[1][ni], 0, 0, 0);
        acc[0][ni] = __builtin_amdgcn_mfma_f32_16x16x32_bf16(a0, bl, acc[0][ni], 0, 0, 0);
        acc[1][ni] = __builtin_amdgcn_mfma_f32_16x16x32_bf16(a1, bl, acc[1][ni], 0, 0, 0);
      }
    }
  }

  // epilogue: D col=lane&15, row=(lane>>4)*4+r
  #pragma unroll
  for (int mi = 0; mi < 2; ++mi) {
    #pragma unroll
    for (int ni = 0; ni < 4; ++ni) {
      int col = wc * 64 + ni * 16 + l15;
      float bv = bias[col];
      #pragma unroll
      for (int r = 0; r < 4; ++r) {
        int gr = row0 + wr * 32 + mi * 16 + l4 * 4 + r;
        if (gr >= M) continue;
        float v = acc[mi][ni][r] + bv;
        u16* op = out + (size_t)gr * HD + col;
        if (MODE == 0) {
          v = fmaxf(v, 0.f);
        } else if (MODE == 2) {
          float pv = bf2f(*op);
          v = fmaxf(0.5f * (v + pv), 0.f);
        }
        *op = f2bf(v);
      }
    }
  }
}

// ---------------- batched mean pool ----------------
__device__ inline int lower_bound_i(const int* __restrict__ a, int n, int v) {
  int lo = 0, hi = n;
  while (lo < hi) {
    int m = (lo + hi) >> 1;
    if (a[m] < v) lo = m + 1; else hi = m;
  }
  return lo;
}

__global__ void pool_kernel(const u16* __restrict__ hx, const int* __restrict__ batch,
                            int n, float* __restrict__ pooled, int ofs) {
  int b = blockIdx.x;
  int h = threadIdx.x;  // 128
  int lo = lower_bound_i(batch, n, b);
  int hi = lower_bound_i(batch, n, b + 1);
  float acc = 0.0f;
  for (int i = lo; i < hi; ++i) acc += bf2f(hx[(size_t)i * HD + h]);
  int cnt = hi - lo; if (cnt < 1) cnt = 1;
  pooled[(size_t)b * 384 + ofs + h] = acc / (float)cnt;
}

// ---------------- final dense ----------------
__global__ void final_kernel(const float* __restrict__ pooled, const float* __restrict__ scalars,
                             const float* __restrict__ Wf, const float* __restrict__ bf,
                             float* __restrict__ out) {
  int b = blockIdx.x;
  int j = threadIdx.x;  // 128
  float acc = bf[j];
  const float* pr = pooled + (size_t)b * 384;
  for (int k = 0; k < 384; ++k) acc = fmaf(pr[k], Wf[(size_t)k * 128 + j], acc);
  const float* sr = scalars + (size_t)b * NSCA;
  for (int s = 0; s < NSCA; ++s) acc = fmaf(sr[s], Wf[(size_t)(384 + s) * 128 + j], acc);
  out[(size_t)b * 128 + j] = acc;
}

extern "C" void kernel_launch(void* const* d_in, const int* in_sizes, int n_in,
                              void* d_out, int out_size, void* d_ws, size_t ws_size,
                              hipStream_t stream) {
  const float* x_hex   = (const float*)d_in[0];
  const float* x_vert  = (const float*)d_in[1];
  const float* x_edge  = (const float*)d_in[2];
  const float* scalars = (const float*)d_in[3];
  const int* src_hv = (const int*)d_in[4];
  const int* dst_hv = (const int*)d_in[5];
  const int* src_vh = (const int*)d_in[6];
  const int* dst_vh = (const int*)d_in[7];
  const int* src_ve = (const int*)d_in[8];
  const int* dst_ve = (const int*)d_in[9];
  const int* src_ev = (const int*)d_in[10];
  const int* dst_ev = (const int*)d_in[11];
  const int* batch_hex  = (const int*)d_in[12];
  const int* batch_vert = (const int*)d_in[13];
  const int* batch_edge = (const int*)d_in[14];
  const float* W_ph = (const float*)d_in[15];
  const float* b_ph = (const float*)d_in[16];
  const float* W_pv = (const float*)d_in[17];
  const float* b_pv = (const float*)d_in[18];
  const float* W_pe = (const float*)d_in[19];
  const float* b_pe = (const float*)d_in[20];
  const float* conv_Wl = (const float*)d_in[21];
  const float* conv_Wr = (const float*)d_in[22];
  const float* conv_b  = (const float*)d_in[23];
  const float* W_final = (const float*)d_in[24];
  const float* b_final = (const float*)d_in[25];
  float* out = (float*)d_out;

  // ---- workspace layout (~165 MB) ----
  char* wp = (char*)d_ws;
  size_t off = 0;
  auto alloc = [&](size_t bytes) -> void* {
    void* p = wp + off;
    off += (bytes + 511) & ~(size_t)511;
    return p;
  };
  u16* hbuf[2]; u16* vbuf[2]; u16* ebuf[2];
  hbuf[0] = (u16*)alloc((size_t)NH_N * HD * 2);
  hbuf[1] = (u16*)alloc((size_t)NH_N * HD * 2);
  vbuf[0] = (u16*)alloc((size_t)NV_N * HD * 2);
  vbuf[1] = (u16*)alloc((size_t)NV_N * HD * 2);
  ebuf[0] = (u16*)alloc((size_t)NE_N * HD * 2);
  ebuf[1] = (u16*)alloc((size_t)NE_N * HD * 2);
  u16* Wt = (u16*)alloc((size_t)12 * 2 * HD * 256 * 2);
  int* degfil = (int*)alloc((size_t)800000 * 4);
  int* deg_hv = degfil + 0;
  int* deg_vh = degfil + NV_N;
  int* deg_ve = degfil + NV_N + NH_N;
  int* deg_ev = degfil + NV_N + NH_N + NE_N;
  int* fil_hv = degfil + 400000;
  int* fil_vh = fil_hv + NV_N;
  int* fil_ve = fil_hv + NV_N + NH_N;
  int* fil_ev = fil_hv + NV_N + NH_N + NE_N;
  int* rp_hv = (int*)alloc((size_t)(NV_N + 1) * 4);
  int* rp_vh = (int*)alloc((size_t)(NH_N + 1) * 4);
  int* rp_ve = (int*)alloc((size_t)(NE_N + 1) * 4);
  int* rp_ev = (int*)alloc((size_t)(NV_N + 1) * 4);
  int* csr_hv = (int*)alloc((size_t)E_N * 4);
  int* csr_vh = (int*)alloc((size_t)E_N * 4);
  int* csr_ve = (int*)alloc((size_t)E_N * 4);
  int* csr_ev = (int*)alloc((size_t)E_N * 4);
  int* bsums  = (int*)alloc(1024 * 4);
  float* pooled = (float*)alloc((size_t)NBAT * 384 * 4);

  // ---- weight prep + zero deg/fil ----
  wprep_kernel<<<dim3(12, 2), 256, 0, stream>>>(conv_Wl, conv_Wr, Wt);
  zero_kernel<<<(800000 + 255) / 256, 256, 0, stream>>>(degfil, 800000);

  // ---- CSR builds ----
  auto build_csr = [&](const int* srcI, const int* dstI, int ndst,
                       int* deg, int* rp, int* fil, int* csr) {
    hist_kernel<<<(E_N + 255) / 256, 256, 0, stream>>>(dstI, deg, E_N);
    int nb = (ndst + 255) / 256;
    scan_block_kernel<<<nb, 256, 0, stream>>>(deg, rp, bsums, ndst);
    scan_sums_kernel<<<1, 256, 0, stream>>>(bsums, nb);
    scan_add_kernel<<<nb, 256, 0, stream>>>(bsums, rp, ndst);
    fill_csr_kernel<<<(E_N + 255) / 256, 256, 0, stream>>>(srcI, dstI, rp, fil, csr, E_N);
  };
  build_csr(src_hv, dst_hv, NV_N, deg_hv, rp_hv, fil_hv, csr_hv);
  build_csr(src_vh, dst_vh, NH_N, deg_vh, rp_vh, fil_vh, csr_vh);
  build_csr(src_ve, dst_ve, NE_N, deg_ve, rp_ve, fil_ve, csr_ve);
  build_csr(src_ev, dst_ev, NV_N, deg_ev, rp_ev, fil_ev, csr_ev);

  // ---- input projections ----
  u16 *ch = hbuf[0], *cv = vbuf[0], *ce = ebuf[0];
  u16 *nh = hbuf[1], *nv = vbuf[1], *ne = ebuf[1];
  proj_kernel<<<NH_N / 2, 256, 0, stream>>>(x_hex, W_ph, b_ph, ch, NH_N, 16);
  proj_kernel<<<NV_N / 2, 256, 0, stream>>>(x_vert, W_pv, b_pv, cv, NV_N, 10);
  proj_kernel<<<NE_N / 2, 256, 0, stream>>>(x_edge, W_pe, b_pe, ce, NE_N, 8);

  // ---- layers ----
  // Wt matrix (l, rel): Wt + ((l*4+rel)*2)*HD*256  (s packed inside: +HD*256 for Wr)
  for (int l = 0; l < NLAY; ++l) {
    const u16* Wt0 = Wt + (size_t)((l * 4 + 0) * 2) * HD * 256;
    const u16* Wt1 = Wt + (size_t)((l * 4 + 1) * 2) * HD * 256;
    const u16* Wt2 = Wt + (size_t)((l * 4 + 2) * 2) * HD * 256;
    const u16* Wt3 = Wt + (size_t)((l * 4 + 3) * 2) * HD * 256;
    const float* bc0 = conv_b + ((size_t)l * 4 + 0) * HD;
    const float* bc1 = conv_b + ((size_t)l * 4 + 1) * HD;
    const float* bc2 = conv_b + ((size_t)l * 4 + 2) * HD;
    const float* bc3 = conv_b + ((size_t)l * 4 + 3) * HD;

    // rel 0 hex->vert: mean(ch) -> stash nv; GEMM in-place (raw t into nv)
    agg_kernel<<<NV_N / 2, 256, 0, stream>>>(ch, rp_hv, csr_hv, nv, NV_N);
    sage_mfma_kernel<1><<<(NV_N + 63) / 64, 256, 0, stream>>>(nv, cv, Wt0, bc0, nv, NV_N);
    // rel 3 edge->vert: mean(ce) -> stash ne (NV rows); combine into nv
    agg_kernel<<<NV_N / 2, 256, 0, stream>>>(ce, rp_ev, csr_ev, ne, NV_N);
    sage_mfma_kernel<2><<<(NV_N + 63) / 64, 256, 0, stream>>>(ne, cv, Wt3, bc3, nv, NV_N);
    // rel 1 vert->hex: mean(cv) -> stash nh; GEMM in-place relu
    agg_kernel<<<NH_N / 2, 256, 0, stream>>>(cv, rp_vh, csr_vh, nh, NH_N);
    sage_mfma_kernel<0><<<(NH_N + 63) / 64, 256, 0, stream>>>(nh, ch, Wt1, bc1, nh, NH_N);
    // rel 2 vert->edge: mean(cv) -> stash ne; GEMM in-place relu
    agg_kernel<<<NE_N / 2, 256, 0, stream>>>(cv, rp_ve, csr_ve, ne, NE_N);
    sage_mfma_kernel<0><<<(NE_N + 63) / 64, 256, 0, stream>>>(ne, ce, Wt2, bc2, ne, NE_N);

    u16* t;
    t = ch; ch = nh; nh = t;
    t = cv; cv = nv; nv = t;
    t = ce; ce = ne; ne = t;
  }

  // ---- pooling + final dense ----
  pool_kernel<<<NBAT, 128, 0, stream>>>(ch, batch_hex, NH_N, pooled, 0);
  pool_kernel<<<NBAT, 128, 0, stream>>>(cv, batch_vert, NV_N, pooled, 128);
  pool_kernel<<<NBAT, 128, 0, stream>>>(ce, batch_edge, NE_N, pooled, 256);
  final_kernel<<<NBAT, 128, 0, stream>>>(pooled, scalars, W_final, b_final, out);
}